// Round 1
// baseline (347.635 us; speedup 1.0000x reference)
//
#include <hip/hip_runtime.h>
#include <stdint.h>

#define NBOX 25200
#define BATCH 32
#define TOPK 1024
#define MAXDET 300
#define CAND 2048
#define CONF_T 0.25f
#define IOU_T 0.45f

__device__ __forceinline__ uint32_t fkey(float f) {
    uint32_t u = __float_as_uint(f);
    return (u & 0x80000000u) ? ~u : (u | 0x80000000u);
}

__device__ __forceinline__ float fkey_inv(uint32_t key) {
    uint32_t u = (key & 0x80000000u) ? (key & 0x7FFFFFFFu) : ~key;
    return __uint_as_float(u);
}

__global__ __launch_bounds__(1024) void nms_kernel(const float* __restrict__ x,
                                                   float* __restrict__ out) {
    const int b = blockIdx.x;
    const int tid = threadIdx.x;
    const float* __restrict__ xb = x + (size_t)b * NBOX * 6;

    __shared__ uint32_t hist[256];
    __shared__ uint32_t sh_prefix, sh_remk, sh_cnt;
    __shared__ unsigned long long keys[CAND];
    __shared__ float bx1[TOPK], by1[TOPK], bx2[TOPK], by2[TOPK], bar[TOPK], bsc[TOPK];
    __shared__ int keep[TOPK];
    __shared__ int wcnt[16], wpre[16];
    __shared__ int sh_total;

    // ---------- radix select: key value of the TOPK-th largest score ----------
    uint32_t prefix = 0;
    uint32_t remk = TOPK;
    for (int pass = 0; pass < 4; ++pass) {
        const int shift = 24 - 8 * pass;
        const uint32_t mask_hi = (pass == 0) ? 0u : (0xFFFFFFFFu << (shift + 8));
        if (tid < 256) hist[tid] = 0;
        __syncthreads();
        for (int n = tid; n < NBOX; n += 1024) {
            float conf = xb[n * 6 + 4] * xb[n * 6 + 5];
            float s = (conf > CONF_T) ? conf : -1.0f;
            uint32_t key = fkey(s);
            if ((key & mask_hi) == prefix)
                atomicAdd(&hist[(key >> shift) & 0xFFu], 1u);
        }
        __syncthreads();
        if (tid == 0) {
            uint32_t cum = 0, sel = 0, rk = remk;
            for (int bin = 255; bin >= 0; --bin) {
                uint32_t c = hist[bin];
                if (cum + c >= rk) { sel = (uint32_t)bin; rk -= cum; break; }
                cum += c;
            }
            sh_prefix = prefix | (sel << shift);
            sh_remk = rk;
        }
        __syncthreads();
        prefix = sh_prefix;
        remk = sh_remk;
        __syncthreads();
    }
    const uint32_t thr_key = prefix;

    // ---------- compact: all elements with key >= thr_key ----------
    if (tid == 0) sh_cnt = 0;
    for (int i = tid; i < CAND; i += 1024) keys[i] = 0ull;
    __syncthreads();
    for (int n = tid; n < NBOX; n += 1024) {
        float conf = xb[n * 6 + 4] * xb[n * 6 + 5];
        float s = (conf > CONF_T) ? conf : -1.0f;
        uint32_t key = fkey(s);
        if (key >= thr_key) {
            uint32_t pos = atomicAdd(&sh_cnt, 1u);
            if (pos < CAND)
                keys[pos] = ((unsigned long long)key << 32) | (uint32_t)(~(uint32_t)n);
        }
    }
    __syncthreads();

    // ---------- bitonic sort, descending by (score key, then smaller idx) ----------
    for (int k = 2; k <= CAND; k <<= 1) {
        for (int j = k >> 1; j > 0; j >>= 1) {
            for (int e = tid; e < CAND; e += 1024) {
                int ixj = e ^ j;
                if (ixj > e) {
                    unsigned long long a = keys[e], c = keys[ixj];
                    bool up = ((e & k) == 0);           // up-segments: descending
                    bool sw = up ? (a < c) : (a > c);
                    if (sw) { keys[e] = c; keys[ixj] = a; }
                }
            }
            __syncthreads();
        }
    }

    // ---------- gather top-K boxes into LDS ----------
    {
        unsigned long long kk = keys[tid];          // first TOPK entries are real
        uint32_t key32 = (uint32_t)(kk >> 32);
        int n = (int)(~(uint32_t)kk);
        float s = fkey_inv(key32);
        float cx = xb[n * 6 + 0], cy = xb[n * 6 + 1];
        float w  = xb[n * 6 + 2], h  = xb[n * 6 + 3];
        float x1 = cx - w * 0.5f, y1 = cy - h * 0.5f;
        float x2 = cx + w * 0.5f, y2 = cy + h * 0.5f;
        bx1[tid] = x1; by1[tid] = y1; bx2[tid] = x2; by2[tid] = y2;
        bar[tid] = (x2 - x1) * (y2 - y1);
        bsc[tid] = s;
        keep[tid] = (s > CONF_T) ? 1 : 0;
    }
    __syncthreads();

    // ---------- greedy sequential NMS (matches reference fori_loop) ----------
    const float my_x1 = bx1[tid], my_y1 = by1[tid];
    const float my_x2 = bx2[tid], my_y2 = by2[tid], my_ar = bar[tid];
    for (int i = 0; i < TOPK; ++i) {
        __syncthreads();
        if (keep[i]) {
            int j = tid;
            if (j > i && keep[j]) {
                float xx1 = fmaxf(bx1[i], my_x1);
                float yy1 = fmaxf(by1[i], my_y1);
                float xx2 = fminf(bx2[i], my_x2);
                float yy2 = fminf(by2[i], my_y2);
                float iw = fmaxf(xx2 - xx1, 0.0f);
                float ih = fmaxf(yy2 - yy1, 0.0f);
                float inter = iw * ih;
                float iou = inter / (bar[i] + my_ar - inter + 1e-9f);
                if (iou > IOU_T) keep[j] = 0;
            }
        }
    }
    __syncthreads();

    // ---------- rank kept entries, write output ----------
    const int lane = tid & 63;
    const int wv = tid >> 6;
    unsigned long long m = __ballot(keep[tid] != 0);
    if (lane == 0) wcnt[wv] = __popcll(m);
    __syncthreads();
    if (tid == 0) {
        int acc = 0;
        for (int w2 = 0; w2 < 16; ++w2) { wpre[w2] = acc; acc += wcnt[w2]; }
        sh_total = acc;
    }
    __syncthreads();
    const int rank = wpre[wv] + (int)__popcll(m & ((1ull << lane) - 1ull));
    const int total = sh_total;

    float* __restrict__ ob = out + (size_t)b * MAXDET * 6;
    if (keep[tid] && rank < MAXDET) {
        ob[rank * 6 + 0] = bx1[tid];
        ob[rank * 6 + 1] = by1[tid];
        ob[rank * 6 + 2] = bx2[tid];
        ob[rank * 6 + 3] = by2[tid];
        ob[rank * 6 + 4] = bsc[tid];
        ob[rank * 6 + 5] = 0.0f;
    }
    for (int r = tid; r < MAXDET; r += 1024) {
        if (r >= total) {
            #pragma unroll
            for (int c = 0; c < 6; ++c) ob[r * 6 + c] = 0.0f;
        }
    }
}

extern "C" void kernel_launch(void* const* d_in, const int* in_sizes, int n_in,
                              void* d_out, int out_size, void* d_ws, size_t ws_size,
                              hipStream_t stream) {
    const float* x = (const float*)d_in[0];
    float* out = (float*)d_out;
    hipLaunchKernelGGL(nms_kernel, dim3(BATCH), dim3(1024), 0, stream, x, out);
}

// Round 2
// 194.729 us; speedup vs baseline: 1.7852x; 1.7852x over previous
//
#include <hip/hip_runtime.h>
#include <stdint.h>

#define NBOX 25200
#define BATCH 32
#define TOPK 1024
#define MAXDET 300
#define CAND 2048
#define CONF_T 0.25f
#define IOU_T 0.45f
#define KEY_BIAS 0x3E800001u   // conf > 0.25 => bits(conf) >= 0x3E800001; key = bits - BIAS in [0, 0xFFFFFF]

__global__ __launch_bounds__(1024) void nms_kernel(const float* __restrict__ x,
                                                   float* __restrict__ out) {
    const int b = blockIdx.x;
    const int tid = threadIdx.x;
    const int lane = tid & 63;
    const int wv = tid >> 6;
    const float* __restrict__ xb = x + (size_t)b * NBOX * 6;

    __shared__ unsigned hist[256];
    __shared__ unsigned sh_prefix, sh_remk, sh_cnt;
    __shared__ unsigned long long keys[CAND];
    __shared__ float4 bbox[TOPK];
    __shared__ float bar[TOPK];
    __shared__ int list[2][64];
    __shared__ int listn[2];
    __shared__ int wcnt[16], wpre[16];
    __shared__ int sh_total;

    // ---------- radix select: 24-bit key of the TOPK-th largest conf (>CONF_T only) ----------
    unsigned prefix = 0, remk = TOPK;
    for (int pass = 0; pass < 3; ++pass) {
        const int shift = 16 - 8 * pass;
        const unsigned mhi = (pass == 0) ? 0u
                           : (pass == 1) ? 0x00FF0000u : 0x00FFFF00u;
        if (tid < 256) hist[tid] = 0;
        __syncthreads();
        for (int n = tid; n < NBOX; n += 1024) {
            float2 oc = *reinterpret_cast<const float2*>(xb + n * 6 + 4);
            float conf = oc.x * oc.y;
            if (conf > CONF_T) {
                unsigned key = __float_as_uint(conf) - KEY_BIAS;
                if ((key & mhi) == prefix)
                    atomicAdd(&hist[(key >> shift) & 0xFFu], 1u);
            }
        }
        __syncthreads();
        if (tid < 64) {
            unsigned c0 = hist[tid * 4 + 0], c1 = hist[tid * 4 + 1];
            unsigned c2 = hist[tid * 4 + 2], c3 = hist[tid * 4 + 3];
            unsigned s3 = c3, s2 = c2 + s3, s1 = c1 + s2, s0 = c0 + s1;
            unsigned suf = s0;
            #pragma unroll
            for (int off = 1; off < 64; off <<= 1) {
                unsigned o = (unsigned)__shfl_down((int)suf, off);
                if (lane + off < 64) suf += o;
            }
            unsigned excl = suf - s0;                  // sum over bins in groups > lane
            unsigned S0 = excl + s0, S1 = excl + s1, S2 = excl + s2, S3 = excl + s3;
            // pick t with S(t) >= remk > S(t+1)
            if (S0 >= remk && S1 < remk) { sh_prefix = prefix | ((unsigned)(tid * 4 + 0) << shift); sh_remk = remk - S1; }
            if (S1 >= remk && S2 < remk) { sh_prefix = prefix | ((unsigned)(tid * 4 + 1) << shift); sh_remk = remk - S2; }
            if (S2 >= remk && S3 < remk) { sh_prefix = prefix | ((unsigned)(tid * 4 + 2) << shift); sh_remk = remk - S3; }
            if (S3 >= remk && excl < remk) { sh_prefix = prefix | ((unsigned)(tid * 4 + 3) << shift); sh_remk = remk - excl; }
        }
        __syncthreads();
        prefix = sh_prefix; remk = sh_remk;
    }
    const unsigned thr24 = prefix;

    // ---------- compact all candidates with key >= thr24 ----------
    if (tid == 0) sh_cnt = 0;
    for (int i = tid; i < CAND; i += 1024) keys[i] = 0ull;
    __syncthreads();
    for (int n = tid; n < NBOX; n += 1024) {
        float2 oc = *reinterpret_cast<const float2*>(xb + n * 6 + 4);
        float conf = oc.x * oc.y;
        if (conf > CONF_T) {
            unsigned key = __float_as_uint(conf) - KEY_BIAS;
            if (key >= thr24) {
                unsigned pos = atomicAdd(&sh_cnt, 1u);
                if (pos < CAND)
                    keys[pos] = ((unsigned long long)key << 32) | (unsigned)(~(unsigned)n);
            }
        }
    }
    __syncthreads();
    const unsigned C = sh_cnt;
    const int size = (C <= 1024u) ? 1024 : CAND;

    // ---------- bitonic sort descending by (key, then smaller idx) ----------
    for (int k = 2; k <= size; k <<= 1) {
        for (int j = k >> 1; j > 0; j >>= 1) {
            for (int e = tid; e < size; e += 1024) {
                int ixj = e ^ j;
                if (ixj > e) {
                    unsigned long long a = keys[e], cc = keys[ixj];
                    bool up = ((e & k) == 0);
                    if (up ? (a < cc) : (a > cc)) { keys[e] = cc; keys[ixj] = a; }
                }
            }
            __syncthreads();
        }
    }

    // ---------- gather top-K boxes ----------
    unsigned long long kk = keys[tid];
    unsigned key24 = (unsigned)(kk >> 32);
    int n = (int)(~(unsigned)kk);
    if (n < 0 || n >= NBOX) n = 0;                    // defensive (padding rows)
    float sc_ = __uint_as_float(key24 + KEY_BIAS);    // bit-exact conf
    float2 p01 = *reinterpret_cast<const float2*>(xb + n * 6);
    float2 p23 = *reinterpret_cast<const float2*>(xb + n * 6 + 2);
    float x1 = p01.x - p23.x * 0.5f, y1 = p01.y - p23.y * 0.5f;
    float x2 = p01.x + p23.x * 0.5f, y2 = p01.y + p23.y * 0.5f;
    float4 mybox = make_float4(x1, y1, x2, y2);
    float my_ar = (x2 - x1) * (y2 - y1);
    bbox[tid] = mybox;
    bar[tid] = my_ar;
    bool alive = (kk != 0ull) && (sc_ > CONF_T);
    __syncthreads();

    // ---------- intra-chunk suppression mask (pure geometry, fully parallel) ----------
    const int cbase = tid & ~63;
    unsigned long long my_mask = 0ull;
    for (int i = 0; i < 64; ++i) {
        float4 bi = bbox[cbase + i];
        float ai = bar[cbase + i];
        float xx1 = fmaxf(bi.x, mybox.x);
        float yy1 = fmaxf(bi.y, mybox.y);
        float xx2 = fminf(bi.z, mybox.z);
        float yy2 = fminf(bi.w, mybox.w);
        float iw = fmaxf(xx2 - xx1, 0.0f);
        float ih = fmaxf(yy2 - yy1, 0.0f);
        float inter = iw * ih;
        float iou = inter / (ai + my_ar - inter + 1e-9f);
        if (i < lane && iou > IOU_T) my_mask |= (1ull << i);
    }

    // ---------- blocked greedy NMS: 16 chunks, 1 barrier each ----------
    for (int c = 0; c < 16; ++c) {
        // apply previous chunk's kept list (parallel across all later waves)
        if (c > 0 && wv >= c && alive) {
            const int pb = (c - 1) & 1;
            const int m = listn[pb];
            for (int t = 0; t < m; ++t) {
                int i = list[pb][t];
                float4 bi = bbox[i];
                float ai = bar[i];
                float xx1 = fmaxf(bi.x, mybox.x);
                float yy1 = fmaxf(bi.y, mybox.y);
                float xx2 = fminf(bi.z, mybox.z);
                float yy2 = fminf(bi.w, mybox.w);
                float iw = fmaxf(xx2 - xx1, 0.0f);
                float ih = fmaxf(yy2 - yy1, 0.0f);
                float inter = iw * ih;
                float iou = inter / (ai + my_ar - inter + 1e-9f);
                if (iou > IOU_T) { alive = false; break; }
            }
        }
        // chunk c resolves itself serially in-register (wave-synchronous, no barriers)
        if (wv == c) {
            unsigned long long rem = __ballot(alive);
            unsigned long long kept = 0ull;
            while (rem) {
                int i = __ffsll((long long)rem) - 1;
                kept |= (1ull << i);
                unsigned long long row = __ballot((int)((my_mask >> i) & 1ull));
                rem &= ~row;
                rem &= ~(1ull << i);
            }
            alive = (kept >> lane) & 1ull;
            int nk = __popcll(kept);
            int rk = __popcll(kept & ((1ull << lane) - 1ull));
            if (alive) list[c & 1][rk] = tid;
            if (lane == 0) listn[c & 1] = nk;
        }
        __syncthreads();
    }

    // ---------- rank kept entries, write output ----------
    unsigned long long m = __ballot(alive);
    if (lane == 0) wcnt[wv] = __popcll(m);
    __syncthreads();
    if (tid == 0) {
        int acc = 0;
        for (int w2 = 0; w2 < 16; ++w2) { wpre[w2] = acc; acc += wcnt[w2]; }
        sh_total = acc;
    }
    __syncthreads();
    const int rank = wpre[wv] + (int)__popcll(m & ((1ull << lane) - 1ull));
    const int total = sh_total;

    float* __restrict__ ob = out + (size_t)b * MAXDET * 6;
    if (alive && rank < MAXDET) {
        ob[rank * 6 + 0] = mybox.x;
        ob[rank * 6 + 1] = mybox.y;
        ob[rank * 6 + 2] = mybox.z;
        ob[rank * 6 + 3] = mybox.w;
        ob[rank * 6 + 4] = sc_;
        ob[rank * 6 + 5] = 0.0f;
    }
    for (int r = tid; r < MAXDET; r += 1024) {
        if (r >= total) {
            #pragma unroll
            for (int cc = 0; cc < 6; ++cc) ob[r * 6 + cc] = 0.0f;
        }
    }
}

extern "C" void kernel_launch(void* const* d_in, const int* in_sizes, int n_in,
                              void* d_out, int out_size, void* d_ws, size_t ws_size,
                              hipStream_t stream) {
    const float* x = (const float*)d_in[0];
    float* out = (float*)d_out;
    hipLaunchKernelGGL(nms_kernel, dim3(BATCH), dim3(1024), 0, stream, x, out);
}

// Round 3
// 164.718 us; speedup vs baseline: 2.1105x; 1.1822x over previous
//
#include <hip/hip_runtime.h>
#include <stdint.h>

#define NBOX 25200
#define BATCH 32
#define TOPK 1024
#define MAXDET 300
#define BINCAP 2048
#define CONF_T 0.25f
#define IOU_T 0.45f
#define KEY_BIAS 0x3E800001u   // conf > 0.25 => bits(conf) >= 0x3E800001; key in [0, 0x00FFFFFF]

__global__ __launch_bounds__(1024) void nms_kernel(const float* __restrict__ x,
                                                   float* __restrict__ out) {
    const int b = blockIdx.x;
    const int tid = threadIdx.x;
    const int lane = tid & 63;
    const int wv = tid >> 6;
    const float* __restrict__ xb = x + (size_t)b * NBOX * 6;

    __shared__ unsigned hist[256];
    __shared__ int sh_selbin;
    __shared__ unsigned sh_cnt;
    __shared__ unsigned long long cand[BINCAP];
    __shared__ unsigned long long keys[TOPK];
    __shared__ float4 bbox[TOPK];
    __shared__ float bar[TOPK];
    __shared__ float4 lbox[2][64];
    __shared__ float lar[2][64];
    __shared__ int listn[2];
    __shared__ int wcnt[16], wpre[16];
    __shared__ int sh_total;

    // ---------- sweep 1: 256-bin histogram over key top byte ----------
    if (tid < 256) hist[tid] = 0;
    if (tid == 0) { sh_selbin = 0; sh_cnt = 0; }
    keys[tid] = 0ull;
    __syncthreads();
    #pragma unroll 5
    for (int n = tid; n < NBOX; n += 1024) {
        float2 oc = *reinterpret_cast<const float2*>(xb + n * 6 + 4);
        float conf = oc.x * oc.y;
        if (conf > CONF_T) {
            unsigned key = __float_as_uint(conf) - KEY_BIAS;
            unsigned bin = key >> 16; if (bin > 255u) bin = 255u;
            atomicAdd(&hist[bin], 1u);
        }
    }
    __syncthreads();
    // selbin = smallest bin whose suffix count >= TOPK (stays 0 if total < TOPK)
    if (tid < 64) {
        unsigned c0 = hist[tid*4+0], c1 = hist[tid*4+1];
        unsigned c2 = hist[tid*4+2], c3 = hist[tid*4+3];
        unsigned s3 = c3, s2 = c2 + s3, s1 = c1 + s2, s0 = c0 + s1;
        unsigned suf = s0;
        #pragma unroll
        for (int off = 1; off < 64; off <<= 1) {
            unsigned o = (unsigned)__shfl_down((int)suf, off);
            if (lane + off < 64) suf += o;
        }
        unsigned excl = suf - s0;
        unsigned S0 = excl+s0, S1 = excl+s1, S2 = excl+s2, S3 = excl+s3;
        if (S0 >= TOPK && S1 < TOPK) sh_selbin = tid*4+0;
        if (S1 >= TOPK && S2 < TOPK) sh_selbin = tid*4+1;
        if (S2 >= TOPK && S3 < TOPK) sh_selbin = tid*4+2;
        if (S3 >= TOPK && excl < TOPK) sh_selbin = tid*4+3;
    }
    __syncthreads();
    const unsigned selbin = (unsigned)sh_selbin;

    // ---------- sweep 2: extract all candidates with bin >= selbin ----------
    for (int n = tid; n < NBOX; n += 1024) {
        float2 oc = *reinterpret_cast<const float2*>(xb + n * 6 + 4);
        float conf = oc.x * oc.y;
        bool take = false; unsigned key = 0;
        if (conf > CONF_T) {
            key = __float_as_uint(conf) - KEY_BIAS;
            unsigned bin = key >> 16; if (bin > 255u) bin = 255u;
            take = (bin >= selbin);
        }
        unsigned long long m = __ballot(take);
        unsigned base = 0;
        if (lane == 0 && m) base = atomicAdd(&sh_cnt, (unsigned)__popcll(m));
        base = (unsigned)__shfl((int)base, 0);
        if (take) {
            unsigned pos = base + (unsigned)__popcll(m & ((1ull << lane) - 1ull));
            if (pos < BINCAP)
                cand[pos] = ((unsigned long long)key << 32) | (unsigned)(~(unsigned)n);
        }
    }
    __syncthreads();
    const int C = (int)min(sh_cnt, (unsigned)BINCAP);

    // ---------- rank sort: exact top-1024 by (key desc, idx asc), 1 barrier ----------
    for (int e = tid; e < C; e += 1024) {
        unsigned long long mine = cand[e];
        int rank = 0;
        #pragma unroll 8
        for (int j = 0; j < C; ++j) rank += (cand[j] > mine) ? 1 : 0;
        if (rank < TOPK) keys[rank] = mine;
    }
    __syncthreads();

    // ---------- gather top-K boxes ----------
    unsigned long long kk = keys[tid];
    unsigned key24 = (unsigned)(kk >> 32);
    int n = (int)(~(unsigned)kk);
    bool alive = (kk != 0ull);
    if (n < 0 || n >= NBOX) { n = 0; alive = false; }
    float sc_ = __uint_as_float(key24 + KEY_BIAS);    // bit-exact conf
    float2 p01 = *reinterpret_cast<const float2*>(xb + n * 6);
    float2 p23 = *reinterpret_cast<const float2*>(xb + n * 6 + 2);
    float x1 = p01.x - p23.x * 0.5f, y1 = p01.y - p23.y * 0.5f;
    float x2 = p01.x + p23.x * 0.5f, y2 = p01.y + p23.y * 0.5f;
    float4 mybox = make_float4(x1, y1, x2, y2);
    float my_ar = (x2 - x1) * (y2 - y1);
    bbox[tid] = mybox;
    bar[tid] = my_ar;
    __syncthreads();

    // ---------- intra-chunk suppression mask (parallel) ----------
    const int cbase = tid & ~63;
    unsigned long long my_mask = 0ull;
    #pragma unroll 4
    for (int i = 0; i < 64; ++i) {
        float4 bi = bbox[cbase + i];
        float ai = bar[cbase + i];
        float xx1 = fmaxf(bi.x, mybox.x);
        float yy1 = fmaxf(bi.y, mybox.y);
        float xx2 = fminf(bi.z, mybox.z);
        float yy2 = fminf(bi.w, mybox.w);
        float iw = fmaxf(xx2 - xx1, 0.0f);
        float ih = fmaxf(yy2 - yy1, 0.0f);
        float inter = iw * ih;
        float iou = inter / (ai + my_ar - inter + 1e-9f);
        if (i < lane && iou > IOU_T) my_mask |= (1ull << i);
    }

    // ---------- blocked greedy NMS: 16 chunks, 1 barrier each ----------
    for (int c = 0; c < 16; ++c) {
        if (c > 0 && wv >= c && alive) {
            const int pb = (c - 1) & 1;
            const int m = listn[pb];
            bool sup = false;
            #pragma unroll 2
            for (int t = 0; t < m; ++t) {
                float4 bi = lbox[pb][t];
                float ai = lar[pb][t];
                float xx1 = fmaxf(bi.x, mybox.x);
                float yy1 = fmaxf(bi.y, mybox.y);
                float xx2 = fminf(bi.z, mybox.z);
                float yy2 = fminf(bi.w, mybox.w);
                float iw = fmaxf(xx2 - xx1, 0.0f);
                float ih = fmaxf(yy2 - yy1, 0.0f);
                float inter = iw * ih;
                float iou = inter / (ai + my_ar - inter + 1e-9f);
                sup = sup || (iou > IOU_T);
            }
            alive = !sup;
        }
        if (wv == c) {
            unsigned long long rem = __ballot(alive);
            unsigned long long kept = 0ull;
            while (rem) {
                int i = __ffsll((long long)rem) - 1;
                unsigned long long bit = 1ull << i;
                kept |= bit;
                unsigned long long row = __ballot((unsigned)((my_mask >> i) & 1ull));
                rem &= ~(row | bit);
            }
            alive = (kept >> lane) & 1ull;
            int nk = __popcll(kept);
            int rk = __popcll(kept & ((1ull << lane) - 1ull));
            if (alive) { lbox[c & 1][rk] = mybox; lar[c & 1][rk] = my_ar; }
            if (lane == 0) listn[c & 1] = nk;
        }
        __syncthreads();
    }

    // ---------- rank kept entries, write output ----------
    unsigned long long m = __ballot(alive);
    if (lane == 0) wcnt[wv] = __popcll(m);
    __syncthreads();
    if (tid == 0) {
        int acc = 0;
        for (int w2 = 0; w2 < 16; ++w2) { wpre[w2] = acc; acc += wcnt[w2]; }
        sh_total = acc;
    }
    __syncthreads();
    const int rank = wpre[wv] + (int)__popcll(m & ((1ull << lane) - 1ull));
    const int total = sh_total;

    float* __restrict__ ob = out + (size_t)b * MAXDET * 6;
    if (alive && rank < MAXDET) {
        ob[rank * 6 + 0] = mybox.x;
        ob[rank * 6 + 1] = mybox.y;
        ob[rank * 6 + 2] = mybox.z;
        ob[rank * 6 + 3] = mybox.w;
        ob[rank * 6 + 4] = sc_;
        ob[rank * 6 + 5] = 0.0f;
    }
    for (int r = tid; r < MAXDET; r += 1024) {
        if (r >= total) {
            #pragma unroll
            for (int cc = 0; cc < 6; ++cc) ob[r * 6 + cc] = 0.0f;
        }
    }
}

extern "C" void kernel_launch(void* const* d_in, const int* in_sizes, int n_in,
                              void* d_out, int out_size, void* d_ws, size_t ws_size,
                              hipStream_t stream) {
    const float* x = (const float*)d_in[0];
    float* out = (float*)d_out;
    hipLaunchKernelGGL(nms_kernel, dim3(BATCH), dim3(1024), 0, stream, x, out);
}